// Round 2
// baseline (429.014 us; speedup 1.0000x reference)
//
#include <hip/hip_runtime.h>
#include <hip/hip_cooperative_groups.h>
#include <math.h>

namespace cg = cooperative_groups;

#define B_ 64
#define E_ 512
#define N_ 2048
#define EPSF 1e-8f

// ws layout (float slots)
#define OFF_ROWMEAN 0              // B*E = 32768
#define OFF_ROWINV  32768          // B*E = 32768
#define OFF_COLPART 65536          // 16*B*N = 2097152 (per-echunk colsum partials)
#define OFF_MM      2162688        // 8 u32 (min[3], max[3])
#define OFF_ZPART   2949128        // 4*B*4096 = 1048576 (4 k-slices)

// order-preserving float<->uint map for atomic min/max
__device__ __forceinline__ unsigned mapf(float x) {
    unsigned u = __float_as_uint(x);
    return (u & 0x80000000u) ? ~u : (u | 0x80000000u);
}
__device__ __forceinline__ float unmapf(unsigned m) {
    unsigned u = (m & 0x80000000u) ? (m ^ 0x80000000u) : ~m;
    return __uint_as_float(u);
}

// ---------- kernel 1: fused row stats + column-sum partials (ONE 268MB pass) ----------
// grid (16, B), block 256 = 4 waves; wave w handles rows [ec*32 + w*8, +8).
// Also initializes the global min/max trackers (block (0,0)) so no host memsets needed.
__global__ __launch_bounds__(256) void k_stats(const float* __restrict__ x,
                                               float* __restrict__ rowmean,
                                               float* __restrict__ rowinv,
                                               float* __restrict__ colpart,
                                               unsigned* __restrict__ mm) {
    __shared__ __align__(16) float cs[4][N_];   // 32 KB
    int b = blockIdx.y, ec = blockIdx.x;
    int t = threadIdx.x, w = t >> 6, lane = t & 63;
    if (ec == 0 && b == 0 && t < 3) {
        mm[t] = 0xFFFFFFFFu;      // running min (mapped-uint)
        mm[3 + t] = 0u;           // running max (mapped-uint)
    }
    float colacc[32];
#pragma unroll
    for (int i = 0; i < 32; ++i) colacc[i] = 0.f;
    int ebase = ec * 32 + w * 8;
#pragma unroll 1
    for (int r = 0; r < 8; ++r) {
        int e = ebase + r;
        const float4* row = (const float4*)(x + ((size_t)b * E_ + e) * N_);
        float s = 0.f, sq = 0.f;
#pragma unroll
        for (int i = 0; i < 8; ++i) {
            float4 v = row[lane + 64 * i];
            s += v.x + v.y + v.z + v.w;
            sq = fmaf(v.x, v.x, sq);
            sq = fmaf(v.y, v.y, sq);
            sq = fmaf(v.z, v.z, sq);
            sq = fmaf(v.w, v.w, sq);
            colacc[4 * i + 0] += v.x;
            colacc[4 * i + 1] += v.y;
            colacc[4 * i + 2] += v.z;
            colacc[4 * i + 3] += v.w;
        }
#pragma unroll
        for (int m = 32; m; m >>= 1) {
            s += __shfl_xor(s, m, 64);
            sq += __shfl_xor(sq, m, 64);
        }
        if (lane == 0) {
            float mean = s * (1.0f / N_);
            float var = sq - s * s * (1.0f / N_);
            if (var < 0.f) var = 0.f;
            rowmean[b * E_ + e] = mean;
            rowinv[b * E_ + e] = 1.0f / (sqrtf(var) + EPSF);
        }
    }
    // wave w dumps its 2048 col partials (lane covers cols 4*lane+256*i+{0..3})
    float4* slice = (float4*)cs[w];
#pragma unroll
    for (int i = 0; i < 8; ++i)
        slice[lane + 64 * i] = make_float4(colacc[4 * i], colacc[4 * i + 1],
                                           colacc[4 * i + 2], colacc[4 * i + 3]);
    __syncthreads();
    float* cp = colpart + ((size_t)ec * B_ + b) * N_;
    for (int c = t; c < N_; c += 256)
        cp[c] = cs[0][c] + cs[1][c] + cs[2][c] + cs[3][c];
}

// ---------- kernel 2: Z = Y Y^T ----------
// grid (B, 4), block 256 = 4 waves (128 KB LDS -> 1 block/CU).
// Wave w handles K-chunk kc = blockIdx.y*4 + w (128 cols), computes the full 64x64
// tile in an 8x8 reg tile, then the 4 waves' tiles are summed in LDS so zpart
// is 4 slices. Y[o] = 0.5*((x[8o+3]-m0)*i0 + (x[8o+4]-m1)*i1).
// LDS layout swizzled: word(o, k=4m+j) = o*128 + 4*(m ^ (o>>3)) + j
//  -> b128 reads over rows 8ti+a hit banks 4*((m^ti)&7): conflict-free.
__global__ __launch_bounds__(256) void k_z(const float* __restrict__ x,
                                           const float* __restrict__ rowmean,
                                           const float* __restrict__ rowinv,
                                           float* __restrict__ zpart) {
    __shared__ __align__(16) float Ysh[4 * 64 * 128];   // 128 KB
    int b = blockIdx.x;
    int kcg = blockIdx.y;                 // 0..3
    int t = threadIdx.x;
    int w = t >> 6, lane = t & 63;
    int k0 = (kcg * 4 + w) * 128;
    const float* xb = x + (size_t)b * E_ * N_;
    const float* rm = rowmean + b * E_;
    const float* ri = rowinv + b * E_;
    float* Yw = Ysh + w * (64 * 128);
    int mg = lane >> 1;              // 4-float group index 0..31
    int jj = (lane & 1) * 2;         // position within group
#pragma unroll 4
    for (int o = 0; o < 64; ++o) {
        int r0 = 8 * o + 3, r1 = 8 * o + 4;
        float2 a = *(const float2*)(xb + (size_t)r0 * N_ + k0 + 2 * lane);
        float2 c = *(const float2*)(xb + (size_t)r1 * N_ + k0 + 2 * lane);
        float m0 = rm[r0], s0 = ri[r0];
        float m1 = rm[r1], s1 = ri[r1];
        float2 yv;
        yv.x = 0.5f * ((a.x - m0) * s0 + (c.x - m1) * s1);
        yv.y = 0.5f * ((a.y - m0) * s0 + (c.y - m1) * s1);
        *(float2*)&Yw[o * 128 + 4 * (mg ^ (o >> 3)) + jj] = yv;
    }
    __syncthreads();   // orders LDS writes -> reads (each wave reads only its own Yw)

    int ti = lane >> 3, tj = lane & 7;
    float acc[8][8];
#pragma unroll
    for (int i = 0; i < 8; ++i)
#pragma unroll
        for (int j = 0; j < 8; ++j) acc[i][j] = 0.f;

#pragma unroll 2
    for (int m4 = 0; m4 < 32; ++m4) {
        float4 av[8], bv[8];
#pragma unroll
        for (int a = 0; a < 8; ++a)
            av[a] = *(const float4*)&Yw[(8 * ti + a) * 128 + 4 * (m4 ^ ti)];
#pragma unroll
        for (int c = 0; c < 8; ++c)
            bv[c] = *(const float4*)&Yw[(8 * tj + c) * 128 + 4 * (m4 ^ tj)];
#pragma unroll
        for (int a = 0; a < 8; ++a)
#pragma unroll
            for (int c = 0; c < 8; ++c) {
                acc[a][c] = fmaf(av[a].x, bv[c].x, acc[a][c]);
                acc[a][c] = fmaf(av[a].y, bv[c].y, acc[a][c]);
                acc[a][c] = fmaf(av[a].z, bv[c].z, acc[a][c]);
                acc[a][c] = fmaf(av[a].w, bv[c].w, acc[a][c]);
            }
    }

    __syncthreads();   // all Y reads done; safe to reuse LDS for tile reduce
    // each wave dumps its 64x64 tile to T[w] (first 64 KB of Ysh)
    float* Tw = Ysh + w * 4096;
#pragma unroll
    for (int a = 0; a < 8; ++a) {
        int rr = (8 * ti + a) * 64 + 8 * tj;
        *(float4*)&Tw[rr]     = make_float4(acc[a][0], acc[a][1], acc[a][2], acc[a][3]);
        *(float4*)&Tw[rr + 4] = make_float4(acc[a][4], acc[a][5], acc[a][6], acc[a][7]);
    }
    __syncthreads();
    // 256 threads sum the 4 tiles and emit one zpart slice
    float* zp = zpart + ((size_t)kcg * B_ + b) * 4096;
    for (int i = t; i < 1024; i += 256) {
        float4 s0 = *(const float4*)&Ysh[0 * 4096 + 4 * i];
        float4 s1 = *(const float4*)&Ysh[1 * 4096 + 4 * i];
        float4 s2 = *(const float4*)&Ysh[2 * 4096 + 4 * i];
        float4 s3 = *(const float4*)&Ysh[3 * 4096 + 4 * i];
        float4 r;
        r.x = s0.x + s1.x + s2.x + s3.x;
        r.y = s0.y + s1.y + s2.y + s3.y;
        r.z = s0.z + s1.z + s2.z + s3.z;
        r.w = s0.w + s1.w + s2.w + s3.w;
        *(float4*)&zp[4 * i] = r;
    }
}

// ---------- kernel 3 (cooperative): views + global minmax + normalize, fused ----------
// grid (B, 3), block 256 = 192 blocks << 256 CUs -> trivially co-resident.
// Raw 64x64 values live in REGISTERS across grid.sync(); no raw buffer round-trip.
__global__ __launch_bounds__(256) void k_viewsnorm(const float* __restrict__ rowmean,
                                                   const float* __restrict__ colpart,
                                                   const float* __restrict__ zpart,
                                                   unsigned* __restrict__ mm,
                                                   float* __restrict__ out) {
    int b = blockIdx.x, v = blockIdx.y;
    int t = threadIdx.x;
    __shared__ float g[2116];
    __shared__ int   ti0[64];
    __shared__ int   ti1[64];
    __shared__ float tw[64];
    __shared__ float smin[4], smax[4];

    int gs = (v == 0) ? 23 : 46;
    if (v < 2) {
        int L = (v == 0) ? 512 : 2048;
        int gg = gs * gs;
        for (int i = t; i < gg; i += 256) {
            float val = 0.f;
            if (i < L) {
                if (v == 0) {
                    val = rowmean[b * E_ + i];
                } else {
#pragma unroll
                    for (int ch = 0; ch < 16; ++ch)
                        val += colpart[((size_t)ch * B_ + b) * N_ + i];
                    val *= (1.0f / 512.0f);
                }
            }
            g[i] = val;
        }
        if (t < 64) {
            // replicate np: src=(o+0.5)*(gs/64)-0.5, clip, floor, w after clip
            double scd = (double)gs / 64.0;
            double sp = ((double)t + 0.5) * scd - 0.5;
            if (sp < 0.0) sp = 0.0;
            double up = (double)(gs - 1);
            if (sp > up) sp = up;
            int i0 = (int)sp;
            ti0[t] = i0;
            ti1[t] = (i0 + 1 < gs) ? i0 + 1 : gs - 1;
            tw[t] = (float)(sp - (double)i0);
        }
    }
    __syncthreads();

    float vals[16];
    float lmin = INFINITY, lmax = -INFINITY;
#pragma unroll 1
    for (int it = 0; it < 16; ++it) {
        int pix = t + 256 * it;
        float val;
        if (v == 2) {
            val = 0.f;
#pragma unroll
            for (int s = 0; s < 4; ++s)
                val += zpart[((size_t)s * B_ + b) * 4096 + pix];
        } else {
            int o = pix >> 6, p = pix & 63;
            int i0 = ti0[o], i1 = ti1[o];
            float wh = tw[o];
            int j0 = ti0[p], j1 = ti1[p];
            float ww = tw[p];
            float top = g[i0 * gs + j0] * (1.f - ww) + g[i0 * gs + j1] * ww;
            float bot = g[i1 * gs + j0] * (1.f - ww) + g[i1 * gs + j1] * ww;
            val = top * (1.f - wh) + bot * wh;
        }
        vals[it] = val;
        lmin = fminf(lmin, val);
        lmax = fmaxf(lmax, val);
    }

    int lane = t & 63, wid = t >> 6;
#pragma unroll
    for (int m = 32; m; m >>= 1) {
        lmin = fminf(lmin, __shfl_xor(lmin, m, 64));
        lmax = fmaxf(lmax, __shfl_xor(lmax, m, 64));
    }
    if (lane == 0) { smin[wid] = lmin; smax[wid] = lmax; }
    __syncthreads();
    if (t == 0) {
        float mn = fminf(fminf(smin[0], smin[1]), fminf(smin[2], smin[3]));
        float mx = fmaxf(fmaxf(smax[0], smax[1]), fmaxf(smax[2], smax[3]));
        atomicMin(&mm[v], mapf(mn));
        atomicMax(&mm[3 + v], mapf(mx));
    }

    cg::this_grid().sync();   // all blocks' mm atomics visible after this

    // device-scope atomic loads: bypass any stale L1 copy of mm
    unsigned lou = __hip_atomic_load(&mm[v], __ATOMIC_RELAXED, __HIP_MEMORY_SCOPE_AGENT);
    unsigned hiu = __hip_atomic_load(&mm[3 + v], __ATOMIC_RELAXED, __HIP_MEMORY_SCOPE_AGENT);
    float lo = unmapf(lou);
    float hi = unmapf(hiu);
    float d = hi - lo;
    bool zero = (d < EPSF);
    float inv = 1.0f / (d + EPSF);
    size_t base = ((size_t)b * 3 + v) * 4096;
#pragma unroll 1
    for (int it = 0; it < 16; ++it) {
        int pix = t + 256 * it;
        out[base + pix] = zero ? 0.f : (vals[it] - lo) * inv;
    }
}

extern "C" void kernel_launch(void* const* d_in, const int* in_sizes, int n_in,
                              void* d_out, int out_size, void* d_ws, size_t ws_size,
                              hipStream_t stream) {
    const float* x = (const float*)d_in[0];
    float* ws = (float*)d_ws;
    float* rowmean = ws + OFF_ROWMEAN;
    float* rowinv  = ws + OFF_ROWINV;
    float* colpart = ws + OFF_COLPART;
    unsigned* mm   = (unsigned*)(ws + OFF_MM);
    float* zpart   = ws + OFF_ZPART;
    float* out     = (float*)d_out;

    // mm trackers are initialized by k_stats block (0,0) — no host memsets.
    k_stats<<<dim3(16, B_), 256, 0, stream>>>(x, rowmean, rowinv, colpart, mm);
    k_z<<<dim3(B_, 4), 256, 0, stream>>>(x, rowmean, rowinv, zpart);

    void* args[] = {(void*)&rowmean, (void*)&colpart, (void*)&zpart,
                    (void*)&mm, (void*)&out};
    hipLaunchCooperativeKernel((const void*)k_viewsnorm, dim3(B_, 3), dim3(256),
                               args, 0, stream);
}

// Round 3
// 403.546 us; speedup vs baseline: 1.0631x; 1.0631x over previous
//
#include <hip/hip_runtime.h>
#include <math.h>

#define B_ 64
#define E_ 512
#define N_ 2048
#define EPSF 1e-8f

// ws layout (float slots)
#define OFF_ROWMEAN 0              // B*E = 32768
#define OFF_ROWINV  32768          // B*E = 32768
#define OFF_COLPART 65536          // 16*B*N = 2097152 (per-echunk colsum partials)
#define OFF_MM      2162688        // 8 u32 (min[3], max[3])
#define OFF_RAW     2162696        // B*3*4096 = 786432
#define OFF_ZPART   2949128        // 4*B*4096 = 1048576 (4 k-slices)

// order-preserving float<->uint map for atomic min/max
__device__ __forceinline__ unsigned mapf(float x) {
    unsigned u = __float_as_uint(x);
    return (u & 0x80000000u) ? ~u : (u | 0x80000000u);
}
__device__ __forceinline__ float unmapf(unsigned m) {
    unsigned u = (m & 0x80000000u) ? (m ^ 0x80000000u) : ~m;
    return __uint_as_float(u);
}

// ---------- kernel 1: fused row stats + column-sum partials (ONE 268MB pass) ----------
// grid (16, B), block 256 = 4 waves; wave w handles rows [ec*32 + w*8, +8).
// Also initializes the global min/max trackers (block (0,0)) so no host memsets needed.
__global__ __launch_bounds__(256) void k_stats(const float* __restrict__ x,
                                               float* __restrict__ rowmean,
                                               float* __restrict__ rowinv,
                                               float* __restrict__ colpart,
                                               unsigned* __restrict__ mm) {
    __shared__ __align__(16) float cs[4][N_];   // 32 KB
    int b = blockIdx.y, ec = blockIdx.x;
    int t = threadIdx.x, w = t >> 6, lane = t & 63;
    if (ec == 0 && b == 0 && t < 3) {
        mm[t] = 0xFFFFFFFFu;      // running min (mapped-uint)
        mm[3 + t] = 0u;           // running max (mapped-uint)
    }
    float colacc[32];
#pragma unroll
    for (int i = 0; i < 32; ++i) colacc[i] = 0.f;
    int ebase = ec * 32 + w * 8;
#pragma unroll 1
    for (int r = 0; r < 8; ++r) {
        int e = ebase + r;
        const float4* row = (const float4*)(x + ((size_t)b * E_ + e) * N_);
        float s = 0.f, sq = 0.f;
#pragma unroll
        for (int i = 0; i < 8; ++i) {
            float4 v = row[lane + 64 * i];
            s += v.x + v.y + v.z + v.w;
            sq = fmaf(v.x, v.x, sq);
            sq = fmaf(v.y, v.y, sq);
            sq = fmaf(v.z, v.z, sq);
            sq = fmaf(v.w, v.w, sq);
            colacc[4 * i + 0] += v.x;
            colacc[4 * i + 1] += v.y;
            colacc[4 * i + 2] += v.z;
            colacc[4 * i + 3] += v.w;
        }
#pragma unroll
        for (int m = 32; m; m >>= 1) {
            s += __shfl_xor(s, m, 64);
            sq += __shfl_xor(sq, m, 64);
        }
        if (lane == 0) {
            float mean = s * (1.0f / N_);
            float var = sq - s * s * (1.0f / N_);
            if (var < 0.f) var = 0.f;
            rowmean[b * E_ + e] = mean;
            rowinv[b * E_ + e] = 1.0f / (sqrtf(var) + EPSF);
        }
    }
    // wave w dumps its 2048 col partials (lane covers cols 4*lane+256*i+{0..3})
    float4* slice = (float4*)cs[w];
#pragma unroll
    for (int i = 0; i < 8; ++i)
        slice[lane + 64 * i] = make_float4(colacc[4 * i], colacc[4 * i + 1],
                                           colacc[4 * i + 2], colacc[4 * i + 3]);
    __syncthreads();
    float* cp = colpart + ((size_t)ec * B_ + b) * N_;
    for (int c = t; c < N_; c += 256)
        cp[c] = cs[0][c] + cs[1][c] + cs[2][c] + cs[3][c];
}

// ---------- kernel 2: Z = Y Y^T ----------
// grid (B, 4), block 256 = 4 waves (128 KB LDS -> 1 block/CU).
// Wave w handles K-chunk kc = blockIdx.y*4 + w (128 cols), computes the full 64x64
// tile in an 8x8 reg tile, then the 4 waves' tiles are summed in LDS so zpart
// is 4 slices. Y[o] = 0.5*((x[8o+3]-m0)*i0 + (x[8o+4]-m1)*i1).
// LDS layout swizzled: word(o, k=4m+j) = o*128 + 4*(m ^ (o>>3)) + j
//  -> b128 reads over rows 8ti+a hit banks 4*((m^ti)&7): conflict-free.
__global__ __launch_bounds__(256) void k_z(const float* __restrict__ x,
                                           const float* __restrict__ rowmean,
                                           const float* __restrict__ rowinv,
                                           float* __restrict__ zpart) {
    __shared__ __align__(16) float Ysh[4 * 64 * 128];   // 128 KB
    int b = blockIdx.x;
    int kcg = blockIdx.y;                 // 0..3
    int t = threadIdx.x;
    int w = t >> 6, lane = t & 63;
    int k0 = (kcg * 4 + w) * 128;
    const float* xb = x + (size_t)b * E_ * N_;
    const float* rm = rowmean + b * E_;
    const float* ri = rowinv + b * E_;
    float* Yw = Ysh + w * (64 * 128);
    int mg = lane >> 1;              // 4-float group index 0..31
    int jj = (lane & 1) * 2;         // position within group
#pragma unroll 4
    for (int o = 0; o < 64; ++o) {
        int r0 = 8 * o + 3, r1 = 8 * o + 4;
        float2 a = *(const float2*)(xb + (size_t)r0 * N_ + k0 + 2 * lane);
        float2 c = *(const float2*)(xb + (size_t)r1 * N_ + k0 + 2 * lane);
        float m0 = rm[r0], s0 = ri[r0];
        float m1 = rm[r1], s1 = ri[r1];
        float2 yv;
        yv.x = 0.5f * ((a.x - m0) * s0 + (c.x - m1) * s1);
        yv.y = 0.5f * ((a.y - m0) * s0 + (c.y - m1) * s1);
        *(float2*)&Yw[o * 128 + 4 * (mg ^ (o >> 3)) + jj] = yv;
    }
    __syncthreads();   // orders LDS writes -> reads (each wave reads only its own Yw)

    int ti = lane >> 3, tj = lane & 7;
    float acc[8][8];
#pragma unroll
    for (int i = 0; i < 8; ++i)
#pragma unroll
        for (int j = 0; j < 8; ++j) acc[i][j] = 0.f;

#pragma unroll 2
    for (int m4 = 0; m4 < 32; ++m4) {
        float4 av[8], bv[8];
#pragma unroll
        for (int a = 0; a < 8; ++a)
            av[a] = *(const float4*)&Yw[(8 * ti + a) * 128 + 4 * (m4 ^ ti)];
#pragma unroll
        for (int c = 0; c < 8; ++c)
            bv[c] = *(const float4*)&Yw[(8 * tj + c) * 128 + 4 * (m4 ^ tj)];
#pragma unroll
        for (int a = 0; a < 8; ++a)
#pragma unroll
            for (int c = 0; c < 8; ++c) {
                acc[a][c] = fmaf(av[a].x, bv[c].x, acc[a][c]);
                acc[a][c] = fmaf(av[a].y, bv[c].y, acc[a][c]);
                acc[a][c] = fmaf(av[a].z, bv[c].z, acc[a][c]);
                acc[a][c] = fmaf(av[a].w, bv[c].w, acc[a][c]);
            }
    }

    __syncthreads();   // all Y reads done; safe to reuse LDS for tile reduce
    // each wave dumps its 64x64 tile to T[w] (first 64 KB of Ysh)
    float* Tw = Ysh + w * 4096;
#pragma unroll
    for (int a = 0; a < 8; ++a) {
        int rr = (8 * ti + a) * 64 + 8 * tj;
        *(float4*)&Tw[rr]     = make_float4(acc[a][0], acc[a][1], acc[a][2], acc[a][3]);
        *(float4*)&Tw[rr + 4] = make_float4(acc[a][4], acc[a][5], acc[a][6], acc[a][7]);
    }
    __syncthreads();
    // 256 threads sum the 4 tiles and emit one zpart slice
    float* zp = zpart + ((size_t)kcg * B_ + b) * 4096;
    for (int i = t; i < 1024; i += 256) {
        float4 s0 = *(const float4*)&Ysh[0 * 4096 + 4 * i];
        float4 s1 = *(const float4*)&Ysh[1 * 4096 + 4 * i];
        float4 s2 = *(const float4*)&Ysh[2 * 4096 + 4 * i];
        float4 s3 = *(const float4*)&Ysh[3 * 4096 + 4 * i];
        float4 r;
        r.x = s0.x + s1.x + s2.x + s3.x;
        r.y = s0.y + s1.y + s2.y + s3.y;
        r.z = s0.z + s1.z + s2.z + s3.z;
        r.w = s0.w + s1.w + s2.w + s3.w;
        *(float4*)&zp[4 * i] = r;
    }
}

// ---------- kernel 3: build raw 64x64 views + global min/max ----------
// grid (B, 3), block 256. v==2 path fully float4-vectorized (4 iters, not 16).
__global__ __launch_bounds__(256) void k_views(const float* __restrict__ rowmean,
                                               const float* __restrict__ colpart,
                                               const float* __restrict__ zpart,
                                               float* __restrict__ raw,
                                               unsigned* __restrict__ mm) {
    int b = blockIdx.x, v = blockIdx.y;
    int t = threadIdx.x;
    __shared__ float g[2116];
    __shared__ int   ti0[64];
    __shared__ int   ti1[64];
    __shared__ float tw[64];
    __shared__ float smin[4], smax[4];

    int gs = (v == 0) ? 23 : 46;
    if (v < 2) {
        int L = (v == 0) ? 512 : 2048;
        int gg = gs * gs;
        for (int i = t; i < gg; i += 256) {
            float val = 0.f;
            if (i < L) {
                if (v == 0) {
                    val = rowmean[b * E_ + i];
                } else {
#pragma unroll
                    for (int ch = 0; ch < 16; ++ch)
                        val += colpart[((size_t)ch * B_ + b) * N_ + i];
                    val *= (1.0f / 512.0f);
                }
            }
            g[i] = val;
        }
        if (t < 64) {
            // replicate np: src=(o+0.5)*(gs/64)-0.5, clip, floor, w after clip
            double scd = (double)gs / 64.0;
            double sp = ((double)t + 0.5) * scd - 0.5;
            if (sp < 0.0) sp = 0.0;
            double up = (double)(gs - 1);
            if (sp > up) sp = up;
            int i0 = (int)sp;
            ti0[t] = i0;
            ti1[t] = (i0 + 1 < gs) ? i0 + 1 : gs - 1;
            tw[t] = (float)(sp - (double)i0);
        }
    }
    __syncthreads();

    float lmin = INFINITY, lmax = -INFINITY;
    float* rbase = raw + ((size_t)b * 3 + v) * 4096;

    if (v == 2) {
        const float4* z0 = (const float4*)(zpart + ((size_t)0 * B_ + b) * 4096);
        const float4* z1 = (const float4*)(zpart + ((size_t)1 * B_ + b) * 4096);
        const float4* z2 = (const float4*)(zpart + ((size_t)2 * B_ + b) * 4096);
        const float4* z3 = (const float4*)(zpart + ((size_t)3 * B_ + b) * 4096);
        float4* r4 = (float4*)rbase;
#pragma unroll
        for (int it = 0; it < 4; ++it) {
            int i4 = t + 256 * it;
            float4 a = z0[i4], bb = z1[i4], c = z2[i4], d = z3[i4];
            float4 r;
            r.x = a.x + bb.x + c.x + d.x;
            r.y = a.y + bb.y + c.y + d.y;
            r.z = a.z + bb.z + c.z + d.z;
            r.w = a.w + bb.w + c.w + d.w;
            r4[i4] = r;
            lmin = fminf(lmin, fminf(fminf(r.x, r.y), fminf(r.z, r.w)));
            lmax = fmaxf(lmax, fmaxf(fmaxf(r.x, r.y), fmaxf(r.z, r.w)));
        }
    } else {
#pragma unroll 1
        for (int it = 0; it < 16; ++it) {
            int pix = t + 256 * it;
            int o = pix >> 6, p = pix & 63;
            int i0 = ti0[o], i1 = ti1[o];
            float wh = tw[o];
            int j0 = ti0[p], j1 = ti1[p];
            float ww = tw[p];
            float top = g[i0 * gs + j0] * (1.f - ww) + g[i0 * gs + j1] * ww;
            float bot = g[i1 * gs + j0] * (1.f - ww) + g[i1 * gs + j1] * ww;
            float val = top * (1.f - wh) + bot * wh;
            rbase[pix] = val;
            lmin = fminf(lmin, val);
            lmax = fmaxf(lmax, val);
        }
    }

    int lane = t & 63, wid = t >> 6;
#pragma unroll
    for (int m = 32; m; m >>= 1) {
        lmin = fminf(lmin, __shfl_xor(lmin, m, 64));
        lmax = fmaxf(lmax, __shfl_xor(lmax, m, 64));
    }
    if (lane == 0) { smin[wid] = lmin; smax[wid] = lmax; }
    __syncthreads();
    if (t == 0) {
        float mn = fminf(fminf(smin[0], smin[1]), fminf(smin[2], smin[3]));
        float mx = fmaxf(fmaxf(smax[0], smax[1]), fmaxf(smax[2], smax[3]));
        atomicMin(&mm[v], mapf(mn));
        atomicMax(&mm[3 + v], mapf(mx));
    }
}

// ---------- kernel 4: global minmax-normalize -> out (float4 vectorized) ----------
__global__ __launch_bounds__(256) void k_norm(const float* __restrict__ raw,
                                              const unsigned* __restrict__ mm,
                                              float* __restrict__ out) {
    int b = blockIdx.x, v = blockIdx.y;
    int t = threadIdx.x;
    float lo = unmapf(mm[v]);
    float hi = unmapf(mm[3 + v]);
    float d = hi - lo;
    bool zero = (d < EPSF);
    float inv = 1.0f / (d + EPSF);
    size_t base = ((size_t)b * 3 + v) * 4096;
    const float4* r4 = (const float4*)(raw + base);
    float4* o4 = (float4*)(out + base);
#pragma unroll
    for (int it = 0; it < 4; ++it) {
        int i4 = t + 256 * it;
        float4 r = r4[i4];
        float4 o;
        o.x = zero ? 0.f : (r.x - lo) * inv;
        o.y = zero ? 0.f : (r.y - lo) * inv;
        o.z = zero ? 0.f : (r.z - lo) * inv;
        o.w = zero ? 0.f : (r.w - lo) * inv;
        o4[i4] = o;
    }
}

extern "C" void kernel_launch(void* const* d_in, const int* in_sizes, int n_in,
                              void* d_out, int out_size, void* d_ws, size_t ws_size,
                              hipStream_t stream) {
    const float* x = (const float*)d_in[0];
    float* ws = (float*)d_ws;
    float* rowmean = ws + OFF_ROWMEAN;
    float* rowinv  = ws + OFF_ROWINV;
    float* colpart = ws + OFF_COLPART;
    unsigned* mm   = (unsigned*)(ws + OFF_MM);
    float* raw     = ws + OFF_RAW;
    float* zpart   = ws + OFF_ZPART;
    float* out     = (float*)d_out;

    // mm trackers are initialized by k_stats block (0,0) — no host memsets.
    // Regular dispatches ONLY: R2 showed hipLaunchCooperativeKernel costs ~20us
    // of per-iteration launch overhead in this harness.
    k_stats<<<dim3(16, B_), 256, 0, stream>>>(x, rowmean, rowinv, colpart, mm);
    k_z<<<dim3(B_, 4), 256, 0, stream>>>(x, rowmean, rowinv, zpart);
    k_views<<<dim3(B_, 3), 256, 0, stream>>>(rowmean, colpart, zpart, raw, mm);
    k_norm<<<dim3(B_, 3), 256, 0, stream>>>(raw, mm, out);
}